// Round 15
// baseline (14779.160 us; speedup 1.0000x reference)
//
#include <hip/hip_runtime.h>
#include <math.h>

#define Bc 16
#define Tc 2048
#define Dc 512
#define Hc 1024
#define Rc 16

// ---------------------------------------------------------------------------
// MEGA KERNEL, one dispatch, 6400 blocks x 256 threads:
//   bid   0..255  : rec role   (byte-equivalent to the R8/R13-proven kernel)
//   bid 256..2303 : xw = X@Wx tile
//   bid 2304..4351: v  = X@Wv tile
//   bid 4352..6399: q/k/lambda for rows (bid-4352)*16 .. +15
// proj GEMM: plain cached float4 stores -> __syncthreads (vmcnt drained,
// stores in XCD L2) -> tid0: fence(release, agent) = buffer_wbl2 writeback
// to the IF$ coherence point (NO invalidate) -> flag store sc0 sc1.
// Consumers read each proj line once, after the flag; start-of-dispatch
// acquire invalidated caches, so plain consumer loads are fresh.
// __launch_bounds__(256,2) caps VGPR at 256 => 2 blocks/CU guaranteed =>
// proj blocks always co-resident with spinning rec blocks (no deadlock).
// ---------------------------------------------------------------------------
__global__ __launch_bounds__(256, 2) void mega(
    const float* __restrict__ X,
    const float* __restrict__ Wx, const float* __restrict__ Wv,
    const float* __restrict__ Wq, const float* __restrict__ Wk,
    const float* __restrict__ Wd, const float* __restrict__ bd,
    const float* __restrict__ Wh, const float* __restrict__ bias,
    float* __restrict__ out0, float* __restrict__ hfin,
    float* __restrict__ Ffin,
    float* __restrict__ vg, float* __restrict__ qg, float* __restrict__ kg,
    float* __restrict__ lamg, float* __restrict__ hbuf,
    int* __restrict__ xcc_tab,
    int* __restrict__ fxw, int* __restrict__ fv, int* __restrict__ fqkl)
{
    __shared__ float smem[8192];   // 32 KB, overlaid per role
    const int tid = threadIdx.x;
    const int bid = blockIdx.x;

    if (bid >= 256) {
        const int pb = bid - 256;
        if (pb < 4096) {
            // ---------------- GEMM path (xw or v) ----------------
            const int which = pb >> 11;        // 0: xw, 1: v
            const int idx = pb & 2047;
            const int mblk = idx >> 3, nblk = idx & 7;
            float (*As)[128] = (float (*)[128])smem;
            float (*Bs)[128] = (float (*)[128])(smem + 2048);
            const float* W = which ? Wv : Wx;
            float* out     = which ? vg : out0;
            const int m0 = mblk * 128;
            const int n0 = nblk * 128;
            const int tx = tid & 15, ty = tid >> 4;
            const int ar = tid >> 1, ak = (tid & 1) * 8;
            const int br = tid >> 4, bn = (tid & 15) * 8;
            float acc[8][8] = {};
            for (int k0 = 0; k0 < 512; k0 += 16) {
                if (k0) __syncthreads();
                float4 a0 = *(const float4*)&X[(size_t)(m0 + ar) * 512 + k0 + ak];
                float4 a1 = *(const float4*)&X[(size_t)(m0 + ar) * 512 + k0 + ak + 4];
                float4 b0 = *(const float4*)&W[(size_t)(k0 + br) * 1024 + n0 + bn];
                float4 b1 = *(const float4*)&W[(size_t)(k0 + br) * 1024 + n0 + bn + 4];
                As[ak + 0][ar] = a0.x; As[ak + 1][ar] = a0.y;
                As[ak + 2][ar] = a0.z; As[ak + 3][ar] = a0.w;
                As[ak + 4][ar] = a1.x; As[ak + 5][ar] = a1.y;
                As[ak + 6][ar] = a1.z; As[ak + 7][ar] = a1.w;
                *(float4*)&Bs[br][bn]     = b0;
                *(float4*)&Bs[br][bn + 4] = b1;
                __syncthreads();
                #pragma unroll
                for (int kk = 0; kk < 16; ++kk) {
                    float4 xa = *(const float4*)&As[kk][ty * 8];
                    float4 xb = *(const float4*)&As[kk][ty * 8 + 4];
                    float4 ya = *(const float4*)&Bs[kk][tx * 8];
                    float4 yb = *(const float4*)&Bs[kk][tx * 8 + 4];
                    float a[8] = {xa.x, xa.y, xa.z, xa.w, xb.x, xb.y, xb.z, xb.w};
                    float b[8] = {ya.x, ya.y, ya.z, ya.w, yb.x, yb.y, yb.z, yb.w};
                    #pragma unroll
                    for (int i = 0; i < 8; ++i)
                        #pragma unroll
                        for (int j = 0; j < 8; ++j)
                            acc[i][j] += a[i] * b[j];
                }
            }
            #pragma unroll
            for (int i = 0; i < 8; ++i) {
                float4 r0, r1;
                r0.x = acc[i][0]; r0.y = acc[i][1]; r0.z = acc[i][2]; r0.w = acc[i][3];
                r1.x = acc[i][4]; r1.y = acc[i][5]; r1.z = acc[i][6]; r1.w = acc[i][7];
                float* op = &out[(size_t)(m0 + ty * 8 + i) * 1024 + n0 + tx * 8];
                *(float4*)op       = r0;      // plain cached stores (fast)
                *(float4*)(op + 4) = r1;
            }
            __syncthreads();                  // drains vmcnt: stores in L2
            if (tid == 0) {
                // release fence: buffer_wbl2 writeback to IF$ (no invalidate)
                __builtin_amdgcn_fence(__ATOMIC_RELEASE, "agent");
                int one = 1;
                int* fp = (which ? fv : fxw) + idx;
                asm volatile("global_store_dword %0, %1, off sc0 sc1"
                             :: "v"(fp), "v"(one) : "memory");
            }
        } else {
            // ---------------- q/k/lambda path ----------------
            const int rb = pb - 4096;          // 0..2047, rows rb*16..+15
            float* xs = smem;                  // 16 rows x 512
            const size_t row0 = (size_t)rb * 16;
            #pragma unroll
            for (int c = 0; c < 8; ++c) {
                int f = (c * 256 + tid) * 4;
                *(float4*)&xs[f] = *(const float4*)&X[row0 * 512 + f];
            }
            __syncthreads();
            for (int t = tid; t < 528; t += 256) {
                int r = t / 33, c = t - r * 33;
                const float* xr = &xs[r * 512];
                const float* Wp; int ldw;
                if (c < 16)      { Wp = Wq + c;        ldw = 16; }
                else if (c < 32) { Wp = Wk + (c - 16); ldw = 16; }
                else             { Wp = Wd;            ldw = 1;  }
                float s = 0.f;
                for (int kk = 0; kk < 512; ++kk) s += xr[kk] * Wp[(size_t)kk * ldw];
                if (c < 16)      qg[(row0 + r) * 16 + c] = s;
                else if (c < 32) kg[(row0 + r) * 16 + (c - 16)] = s;
                else             lamg[row0 + r] = 1.f / (1.f + expf(-(s + bd[0])));
            }
            __syncthreads();                  // drains vmcnt: stores in L2
            if (tid == 0) {
                __builtin_amdgcn_fence(__ATOMIC_RELEASE, "agent");
                int one = 1;
                int* fp = fqkl + rb;
                asm volatile("global_store_dword %0, %1, off sc0 sc1"
                             :: "v"(fp), "v"(one) : "memory");
            }
        }
        return;
    }

    // ======================= rec role (R8-proven) =======================
    float* hs       = smem;                     // 2*1152 = 2304
    float* red2     = smem + 2304;              // 2*256
    float* pre_lds  = smem + 2816;              // 2*64
    float (*F_lds)[17] = (float (*)[17])(smem + 2944);  // 64*17

    const int g = bid & 7, sl = bid >> 3;
    const int c0 = sl * 32;
    const int kp = tid >> 3;
    const int cu = tid & 7;
    const int wv = tid >> 6;

    const int my_xcc = __builtin_amdgcn_s_getreg(63508) & 0xF; // hwreg XCC_ID
    if (tid == 0) {
        int val = my_xcc + 1;
        int* tp = xcc_tab + bid;
        asm volatile("global_store_dword %0, %1, off sc0 sc1"
                     :: "v"(tp), "v"(val) : "memory");
    }

    float wr[128];
    #pragma unroll
    for (int i = 0; i < 32; ++i) {
        float4 w4 = *(const float4*)&Wh[(size_t)(kp * 32 + i) * 1024 + c0 + cu * 4];
        wr[i * 4 + 0] = w4.x; wr[i * 4 + 1] = w4.y;
        wr[i * 4 + 2] = w4.z; wr[i * 4 + 3] = w4.w;
    }

    const int sb_ = tid >> 7;
    const int f   = (tid & 127) * 8;
    float* stage_base = &hs[sb_ * 1152 + (f >> 5) * 36 + (f & 31)];

    int fastf;
    {
        const int prod_bid = (f >> 5) * 8 + g;
        const int* tp = xcc_tab + prod_bid;
        int tv;
        for (;;) {
            asm volatile("global_load_dword %0, %1, off sc0 sc1\n\t"
                         "s_waitcnt vmcnt(0)"
                         : "=&v"(tv) : "v"(tp) : "memory");
            if (tv != -1) break;
        }
        fastf = ((tv - 1) == my_xcc) ? 1 : 0;
    }

    const int j64 = tid & 63;
    const int fb = j64 >> 5, fci = j64 & 31;
    const int bg = g * 2 + fb;
    const bool isScan = (tid >= 192);
    const bool isFin  = (tid < 64);

    float bias_r = 0.f, plam = 0.f, pv = 0.f, pxw = 0.f;
    float4 pq[4], pk4[4];
    if (isScan) {
        bias_r = bias[c0 + fci];
        #pragma unroll
        for (int r = 0; r < 16; ++r) F_lds[j64][r] = 0.f;
        // flag-wait for row 0 inputs (all lanes same addr -> broadcast)
        {
            const int fidx = (bg * 16 + 0) * 8 + (sl >> 2);
            int fvv;
            const int* fp1 = fxw + fidx;
            for (;;) {
                asm volatile("global_load_dword %0, %1, off sc0 sc1\n\t"
                             "s_waitcnt vmcnt(0)" : "=&v"(fvv) : "v"(fp1) : "memory");
                if (fvv) break;
                __builtin_amdgcn_s_sleep(8);
            }
            const int* fp2 = fv + fidx;
            for (;;) {
                asm volatile("global_load_dword %0, %1, off sc0 sc1\n\t"
                             "s_waitcnt vmcnt(0)" : "=&v"(fvv) : "v"(fp2) : "memory");
                if (fvv) break;
                __builtin_amdgcn_s_sleep(8);
            }
            const int* fp3 = fqkl + bg * 128;
            for (;;) {
                asm volatile("global_load_dword %0, %1, off sc0 sc1\n\t"
                             "s_waitcnt vmcnt(0)" : "=&v"(fvv) : "v"(fp3) : "memory");
                if (fvv) break;
                __builtin_amdgcn_s_sleep(8);
            }
        }
        const size_t row = (size_t)bg * Tc;             // t = 0 inputs
        plam = lamg[row];
        pv   = vg[row * Hc + c0 + fci];
        pxw  = out0[row * Hc + c0 + fci];
        const float* qp  = qg + row * 16;
        const float* kpp = kg + row * 16;
        #pragma unroll
        for (int r4 = 0; r4 < 4; ++r4) {
            pq[r4]  = *(const float4*)(qp + r4 * 4);
            pk4[r4] = *(const float4*)(kpp + r4 * 4);
        }
    }

    for (int t = 0; t < Tc; ++t) {
        const int buf = t & 1;
        float* h_rd = hbuf + (t & 1) * (16 * 1024) + g * 2048;
        float* h_wr = hbuf + ((t + 1) & 1) * (16 * 1024) + g * 2048;
        const float off_r = ((t >> 1) & 1) ? 4.0f : 0.0f;
        const float off_w = (((t + 1) >> 1) & 1) ? 4.0f : 0.0f;

        // ---- wave3: fast-weight scan (hidden under the poll) ----
        if (isScan) {
            float rd = 0.f;
            #pragma unroll
            for (int r4 = 0; r4 < 4; ++r4) {
                float f0 = F_lds[j64][r4 * 4 + 0];
                float f1 = F_lds[j64][r4 * 4 + 1];
                float f2 = F_lds[j64][r4 * 4 + 2];
                float f3 = F_lds[j64][r4 * 4 + 3];
                f0 = plam * f0 + pv * pk4[r4].x; rd += f0 * pq[r4].x;
                f1 = plam * f1 + pv * pk4[r4].y; rd += f1 * pq[r4].y;
                f2 = plam * f2 + pv * pk4[r4].z; rd += f2 * pq[r4].z;
                f3 = plam * f3 + pv * pk4[r4].w; rd += f3 * pq[r4].w;
                F_lds[j64][r4 * 4 + 0] = f0;
                F_lds[j64][r4 * 4 + 1] = f1;
                F_lds[j64][r4 * 4 + 2] = f2;
                F_lds[j64][r4 * 4 + 3] = f3;
            }
            pre_lds[buf * 64 + j64] = pxw + rd + bias_r;
            if (t == Tc - 1) {
                #pragma unroll
                for (int r = 0; r < 16; ++r)
                    Ffin[((size_t)bg * Hc + c0 + fci) * 16 + r] = F_lds[j64][r];
            } else {
                const int trow = t + 1;
                if ((trow & 127) == 0) {
                    const int fidx = (bg * 16 + (trow >> 7)) * 8 + (sl >> 2);
                    int fvv;
                    const int* fp1 = fxw + fidx;
                    for (;;) {
                        asm volatile("global_load_dword %0, %1, off sc0 sc1\n\t"
                                     "s_waitcnt vmcnt(0)" : "=&v"(fvv) : "v"(fp1) : "memory");
                        if (fvv) break;
                        __builtin_amdgcn_s_sleep(8);
                    }
                    const int* fp2 = fv + fidx;
                    for (;;) {
                        asm volatile("global_load_dword %0, %1, off sc0 sc1\n\t"
                                     "s_waitcnt vmcnt(0)" : "=&v"(fvv) : "v"(fp2) : "memory");
                        if (fvv) break;
                        __builtin_amdgcn_s_sleep(8);
                    }
                }
                if ((trow & 15) == 0) {
                    int fvv;
                    const int* fp3 = fqkl + bg * 128 + (trow >> 4);
                    for (;;) {
                        asm volatile("global_load_dword %0, %1, off sc0 sc1\n\t"
                                     "s_waitcnt vmcnt(0)" : "=&v"(fvv) : "v"(fp3) : "memory");
                        if (fvv) break;
                        __builtin_amdgcn_s_sleep(8);
                    }
                }
                const size_t row = (size_t)bg * Tc + trow;
                plam = lamg[row];
                pv   = vg[row * Hc + c0 + fci];
                pxw  = out0[row * Hc + c0 + fci];
                const float* qp  = qg + row * 16;
                const float* kpp = kg + row * 16;
                #pragma unroll
                for (int r4 = 0; r4 < 4; ++r4) {
                    pq[r4]  = *(const float4*)(qp + r4 * 4);
                    pk4[r4] = *(const float4*)(kpp + r4 * 4);
                }
            }
        }

        // ---- poll own 8-value window, stage into hs ----
        if (t > 0) {
            const float lo = off_r - 1.5f, hi = off_r + 1.5f;
            const float* p0 = h_rd + sb_ * 1024 + f;
            const float* p1 = p0 + 4;
            float4 r0, r1;
            int tries = 0;
            for (;;) {
                if (fastf) {
                    asm volatile(
                        "global_load_dwordx4 %0, %2, off sc0\n\t"
                        "global_load_dwordx4 %1, %3, off sc0\n\t"
                        "s_waitcnt vmcnt(0)"
                        : "=&v"(r0), "=&v"(r1)
                        : "v"(p0), "v"(p1) : "memory");
                } else {
                    asm volatile(
                        "global_load_dwordx4 %0, %2, off sc0 sc1\n\t"
                        "global_load_dwordx4 %1, %3, off sc0 sc1\n\t"
                        "s_waitcnt vmcnt(0)"
                        : "=&v"(r0), "=&v"(r1)
                        : "v"(p0), "v"(p1) : "memory");
                }
                bool ok = r0.x > lo && r0.x < hi && r0.y > lo && r0.y < hi
                       && r0.z > lo && r0.z < hi && r0.w > lo && r0.w < hi
                       && r1.x > lo && r1.x < hi && r1.y > lo && r1.y < hi
                       && r1.z > lo && r1.z < hi && r1.w > lo && r1.w < hi;
                if (ok) break;
                if (fastf && ++tries > 64) fastf = 0;  // sticky escalation
            }
            r0.x -= off_r; r0.y -= off_r; r0.z -= off_r; r0.w -= off_r;
            r1.x -= off_r; r1.y -= off_r; r1.z -= off_r; r1.w -= off_r;
            *(float4*)(stage_base)     = r0;
            *(float4*)(stage_base + 4) = r1;
        } else {
            float4 z = {0.f, 0.f, 0.f, 0.f};
            *(float4*)(stage_base)     = z;
            *(float4*)(stage_base + 4) = z;
        }
        __syncthreads();                       // B: hs ready

        // ---- matvec: 16 b128 LDS reads, 256 FMAs per thread ----
        float acc[8];
        #pragma unroll
        for (int z = 0; z < 8; ++z) acc[z] = 0.f;
        #pragma unroll
        for (int bb = 0; bb < 2; ++bb) {
            const float* hb = &hs[bb * 1152 + kp * 36];
            #pragma unroll
            for (int i = 0; i < 8; ++i) {
                float4 h4 = *(const float4*)(hb + i * 4);
                #pragma unroll
                for (int j = 0; j < 4; ++j)
                    acc[j * 2 + bb] += h4.x * wr[(i * 4 + 0) * 4 + j]
                                     + h4.y * wr[(i * 4 + 1) * 4 + j]
                                     + h4.z * wr[(i * 4 + 2) * 4 + j]
                                     + h4.w * wr[(i * 4 + 3) * 4 + j];
            }
        }

        // ---- butterfly over the wave's 8 k-parts (lane bits 3,4,5) ----
        #pragma unroll
        for (int z = 0; z < 8; ++z) {
            float s = acc[z];
            s += __shfl_xor(s, 8);
            s += __shfl_xor(s, 16);
            s += __shfl_xor(s, 32);
            acc[z] = s;
        }
        if (j64 < 8) {
            float4 ra, rb;
            ra.x = acc[0]; ra.y = acc[1]; ra.z = acc[2]; ra.w = acc[3];
            rb.x = acc[4]; rb.y = acc[5]; rb.z = acc[6]; rb.w = acc[7];
            *(float4*)&red2[buf * 256 + wv * 64 + j64 * 8]     = ra;
            *(float4*)&red2[buf * 256 + wv * 64 + j64 * 8 + 4] = rb;
        }
        __syncthreads();                       // C: red2 + pre_lds ready

        // ---- finisher: combine 4 wave-partials, tanh, store ----
        if (isFin) {
            const int cu_f = fci >> 2, jf = fci & 3;
            const int z = jf * 2 + fb;
            float tot = pre_lds[buf * 64 + j64];
            #pragma unroll
            for (int ww = 0; ww < 4; ++ww)
                tot += red2[buf * 256 + ww * 64 + cu_f * 8 + z];
            float hv = tanhf(tot);
            float sv = hv + off_w;             // self-signaling store first
            float* hp = h_wr + fb * 1024 + c0 + fci;
            asm volatile(
                "global_store_dword %0, %1, off sc0 sc1"
                :: "v"(hp), "v"(sv) : "memory");
            size_t oidx = ((size_t)bg * Tc + t) * Hc + c0 + fci;
            out0[oidx] = hv;
            if (t == Tc - 1) hfin[(size_t)bg * Hc + c0 + fci] = hv;
        }
    }
}

// ---------------------------------------------------------------------------
extern "C" void kernel_launch(void* const* d_in, const int* in_sizes, int n_in,
                              void* d_out, int out_size, void* d_ws, size_t ws_size,
                              hipStream_t stream)
{
    const float* x    = (const float*)d_in[0];
    const float* Wx   = (const float*)d_in[1];
    const float* Wh   = (const float*)d_in[2];
    const float* Wq   = (const float*)d_in[3];
    const float* Wk   = (const float*)d_in[4];
    const float* Wv   = (const float*)d_in[5];
    const float* Wd   = (const float*)d_in[6];
    const float* bias = (const float*)d_in[7];
    const float* bd   = (const float*)d_in[8];

    float* out0 = (float*)d_out;                    // (B,T,H): xw, then h
    float* hfin = out0 + (size_t)Bc * Tc * Hc;      // (B,H)
    float* Ffin = hfin + (size_t)Bc * Hc;           // (B,H,R)

    float* wsf  = (float*)d_ws;
    float* v    = wsf;                               // B*T*H
    float* q    = v + (size_t)Bc * Tc * Hc;          // B*T*R
    float* k    = q + (size_t)Bc * Tc * Rc;          // B*T*R
    float* lam  = k + (size_t)Bc * Tc * Rc;          // B*T
    float* hbuf = lam + (size_t)Bc * Tc;             // 2 * B*H ping-pong
    int*   xcc  = (int*)(hbuf + 2 * (size_t)Bc * Hc);// 256 entries
    int*   fxw  = xcc + 256;                         // 2048
    int*   fvf  = fxw + 2048;                        // 2048
    int*   fqkl = fvf + 2048;                        // 2048

    // 0x7F7F7F7F == 3.39e38f: invalid under both offsets -> poll-safe init.
    hipMemsetAsync(hbuf, 0x7F, 2 * (size_t)Bc * Hc * sizeof(float), stream);
    hipMemsetAsync(xcc, 0xFF, 256 * sizeof(int), stream);
    hipMemsetAsync(fxw, 0, 3 * 2048 * sizeof(int), stream);

    mega<<<6400, 256, 0, stream>>>(x, Wx, Wv, Wq, Wk, Wd, bd, Wh, bias,
                                   out0, hfin, Ffin,
                                   v, q, k, lam, hbuf, xcc, fxw, fvf, fqkl);
}

// Round 16
// 7796.870 us; speedup vs baseline: 1.8955x; 1.8955x over previous
//
#include <hip/hip_runtime.h>
#include <math.h>

#define Bc 16
#define Tc 2048
#define Dc 512
#define Hc 1024
#define Rc 16

// ---------------------------------------------------------------------------
// Merged projection kernel. One dispatch, grid (256, 8, 3):
//   z=0: xw = X@Wx   (BM=128, BN=128, 8x8 micro-tile)
//   z=1: v  = X@Wv   (same)
//   z=2: q/k/lambda  (block = 16 rows of x staged in LDS; 528 dots)
// ---------------------------------------------------------------------------
__global__ __launch_bounds__(256) void proj_fused(const float* __restrict__ X,
    const float* __restrict__ Wx, const float* __restrict__ Wv,
    const float* __restrict__ Wq, const float* __restrict__ Wk,
    const float* __restrict__ Wd, const float* __restrict__ bd,
    float* __restrict__ out0, float* __restrict__ vout,
    float* __restrict__ q, float* __restrict__ k, float* __restrict__ lam)
{
    __shared__ float smem[8192];   // 32 KB, shared by both paths
    const int tid = threadIdx.x;

    if (blockIdx.z < 2) {
        // ---------------- GEMM path ----------------
        float (*As)[128] = (float (*)[128])smem;          // [16][128]
        float (*Bs)[128] = (float (*)[128])(smem + 2048); // [16][128]
        const float* W = blockIdx.z ? Wv : Wx;
        float* out     = blockIdx.z ? vout : out0;
        const int m0 = blockIdx.x * 128;
        const int n0 = blockIdx.y * 128;
        const int tx = tid & 15, ty = tid >> 4;
        const int ar = tid >> 1, ak = (tid & 1) * 8;
        const int br = tid >> 4, bn = (tid & 15) * 8;
        float acc[8][8] = {};
        for (int k0 = 0; k0 < 512; k0 += 16) {
            if (k0) __syncthreads();
            float4 a0 = *(const float4*)&X[(size_t)(m0 + ar) * 512 + k0 + ak];
            float4 a1 = *(const float4*)&X[(size_t)(m0 + ar) * 512 + k0 + ak + 4];
            float4 b0 = *(const float4*)&W[(size_t)(k0 + br) * 1024 + n0 + bn];
            float4 b1 = *(const float4*)&W[(size_t)(k0 + br) * 1024 + n0 + bn + 4];
            As[ak + 0][ar] = a0.x; As[ak + 1][ar] = a0.y;
            As[ak + 2][ar] = a0.z; As[ak + 3][ar] = a0.w;
            As[ak + 4][ar] = a1.x; As[ak + 5][ar] = a1.y;
            As[ak + 6][ar] = a1.z; As[ak + 7][ar] = a1.w;
            *(float4*)&Bs[br][bn]     = b0;
            *(float4*)&Bs[br][bn + 4] = b1;
            __syncthreads();
            #pragma unroll
            for (int kk = 0; kk < 16; ++kk) {
                float4 xa = *(const float4*)&As[kk][ty * 8];
                float4 xb = *(const float4*)&As[kk][ty * 8 + 4];
                float4 ya = *(const float4*)&Bs[kk][tx * 8];
                float4 yb = *(const float4*)&Bs[kk][tx * 8 + 4];
                float a[8] = {xa.x, xa.y, xa.z, xa.w, xb.x, xb.y, xb.z, xb.w};
                float b[8] = {ya.x, ya.y, ya.z, ya.w, yb.x, yb.y, yb.z, yb.w};
                #pragma unroll
                for (int i = 0; i < 8; ++i)
                    #pragma unroll
                    for (int j = 0; j < 8; ++j)
                        acc[i][j] += a[i] * b[j];
            }
        }
        #pragma unroll
        for (int i = 0; i < 8; ++i) {
            float4 r0, r1;
            r0.x = acc[i][0]; r0.y = acc[i][1]; r0.z = acc[i][2]; r0.w = acc[i][3];
            r1.x = acc[i][4]; r1.y = acc[i][5]; r1.z = acc[i][6]; r1.w = acc[i][7];
            float* op = &out[(size_t)(m0 + ty * 8 + i) * 1024 + n0 + tx * 8];
            *(float4*)op       = r0;
            *(float4*)(op + 4) = r1;
        }
    } else {
        // ---------------- q/k/lambda path ----------------
        float* xs = smem;                                  // 16 rows x 512
        const int rb = blockIdx.x * 8 + blockIdx.y;        // 0..2047
        const size_t row0 = (size_t)rb * 16;
        #pragma unroll
        for (int c = 0; c < 8; ++c) {
            int f = (c * 256 + tid) * 4;
            *(float4*)&xs[f] = *(const float4*)&X[row0 * 512 + f];
        }
        __syncthreads();
        for (int t = tid; t < 528; t += 256) {
            int r = t / 33, c = t - r * 33;
            const float* xr = &xs[r * 512];
            const float* Wp; int ldw;
            if (c < 16)      { Wp = Wq + c;        ldw = 16; }
            else if (c < 32) { Wp = Wk + (c - 16); ldw = 16; }
            else             { Wp = Wd;            ldw = 1;  }
            float s = 0.f;
            for (int kk = 0; kk < 512; ++kk) s += xr[kk] * Wp[(size_t)kk * ldw];
            if (c < 16)      q[(row0 + r) * 16 + c] = s;
            else if (c < 32) k[(row0 + r) * 16 + (c - 16)] = s;
            else             lam[row0 + r] = 1.f / (1.f + expf(-(s + bd[0])));
        }
    }
}

// ---------------------------------------------------------------------------
// Fused recurrence — R13-proven kernel + ONE delta: DUAL-STORE publish.
// Producer stores h first with sc0 (deposits a VALID line in the shared
// XCD L2 for same-XCD fast polls -- the sc0 sc1 write-through alone leaves
// no L2 copy, so fast polls were missing to IF$ every step), then sc0 sc1
// (coherence point: escalated/slow consumers always make progress).
// Everything else byte-identical; VGPR budget untouched (184).
// ---------------------------------------------------------------------------
__global__ __launch_bounds__(256, 1) void rec_fused(
    const float* __restrict__ Wh, const float* __restrict__ qg,
    const float* __restrict__ kg, const float* __restrict__ vg,
    const float* __restrict__ lamg, const float* __restrict__ bias,
    float* __restrict__ out0, float* __restrict__ hfin,
    float* __restrict__ Ffin, float* __restrict__ hbuf,
    int* __restrict__ xcc_tab)
{
    __shared__ float hs[2 * 1152];     // phys(b,k) = b*1152 + (k>>5)*36 + (k&31)
    __shared__ float red2[2][256];     // [buf][wave*64 + cu*8 + z]
    __shared__ float pre_lds[2][64];   // [buf][bb*32 + ci]
    __shared__ float F_lds[64][17];    // fast-weight state, pad 17

    const int tid = threadIdx.x;
    const int bid = blockIdx.x;
    const int g = bid & 7, sl = bid >> 3;
    const int c0 = sl * 32;
    const int kp = tid >> 3;          // k-part: 32 k's (kp*32 .. +31)
    const int cu = tid & 7;           // col unit: 4 cols (c0 + cu*4 + j)
    const int wv = tid >> 6;

    // ---- publish my XCD id (value xcc+1; table memset to 0xFF each launch)
    const int my_xcc = __builtin_amdgcn_s_getreg(63508) & 0xF; // hwreg XCC_ID
    if (tid == 0) {
        int val = my_xcc + 1;
        int* tp = xcc_tab + bid;
        asm volatile("global_store_dword %0, %1, off sc0 sc1"
                     :: "v"(tp), "v"(val) : "memory");
    }

    // ---- weights: 128 regs/thread, all indices compile-time
    float wr[128];
    #pragma unroll
    for (int i = 0; i < 32; ++i) {
        float4 w4 = *(const float4*)&Wh[(size_t)(kp * 32 + i) * 1024 + c0 + cu * 4];
        wr[i * 4 + 0] = w4.x; wr[i * 4 + 1] = w4.y;
        wr[i * 4 + 2] = w4.z; wr[i * 4 + 3] = w4.w;
    }

    // ---- stage/poll geometry: thread owns 8 h values of one batch
    const int sb_ = tid >> 7;                // batch-in-group 0/1
    const int f   = (tid & 127) * 8;         // col offset 0..1016
    float* stage_base = &hs[sb_ * 1152 + (f >> 5) * 36 + (f & 31)];

    // ---- scope detect: producer of my window
    int fastf;
    {
        const int prod_bid = (f >> 5) * 8 + g;
        const int* tp = xcc_tab + prod_bid;
        int tv;
        for (;;) {
            asm volatile("global_load_dword %0, %1, off sc0 sc1\n\t"
                         "s_waitcnt vmcnt(0)"
                         : "=&v"(tv) : "v"(tp) : "memory");
            if (tv != -1) break;
        }
        fastf = ((tv - 1) == my_xcc) ? 1 : 0;
    }

    // ---- roles
    const int j64 = tid & 63;
    const int fb = j64 >> 5, fci = j64 & 31;   // (batch-in-group, col-in-slice)
    const int bg = g * 2 + fb;                 // global batch
    const bool isScan = (tid >= 192);
    const bool isFin  = (tid < 64);

    float bias_r = 0.f, plam = 0.f, pv = 0.f, pxw = 0.f;
    float4 pq[4], pk4[4];
    if (isScan) {
        bias_r = bias[c0 + fci];
        #pragma unroll
        for (int r = 0; r < 16; ++r) F_lds[j64][r] = 0.f;
        const size_t row = (size_t)bg * Tc;             // t = 0 inputs
        plam = lamg[row];
        pv   = vg[row * Hc + c0 + fci];
        pxw  = out0[row * Hc + c0 + fci];
        const float* qp  = qg + row * 16;
        const float* kpp = kg + row * 16;
        #pragma unroll
        for (int r4 = 0; r4 < 4; ++r4) {
            pq[r4]  = *(const float4*)(qp + r4 * 4);
            pk4[r4] = *(const float4*)(kpp + r4 * 4);
        }
    }

    for (int t = 0; t < Tc; ++t) {
        const int buf = t & 1;
        float* h_rd = hbuf + (t & 1) * (16 * 1024) + g * 2048;
        float* h_wr = hbuf + ((t + 1) & 1) * (16 * 1024) + g * 2048;
        const float off_r = ((t >> 1) & 1) ? 4.0f : 0.0f;
        const float off_w = (((t + 1) >> 1) & 1) ? 4.0f : 0.0f;

        // ---- wave3: fast-weight scan (hidden under the poll) ----
        if (isScan) {
            float rd = 0.f;
            #pragma unroll
            for (int r4 = 0; r4 < 4; ++r4) {
                float f0 = F_lds[j64][r4 * 4 + 0];
                float f1 = F_lds[j64][r4 * 4 + 1];
                float f2 = F_lds[j64][r4 * 4 + 2];
                float f3 = F_lds[j64][r4 * 4 + 3];
                f0 = plam * f0 + pv * pk4[r4].x; rd += f0 * pq[r4].x;
                f1 = plam * f1 + pv * pk4[r4].y; rd += f1 * pq[r4].y;
                f2 = plam * f2 + pv * pk4[r4].z; rd += f2 * pq[r4].z;
                f3 = plam * f3 + pv * pk4[r4].w; rd += f3 * pq[r4].w;
                F_lds[j64][r4 * 4 + 0] = f0;
                F_lds[j64][r4 * 4 + 1] = f1;
                F_lds[j64][r4 * 4 + 2] = f2;
                F_lds[j64][r4 * 4 + 3] = f3;
            }
            pre_lds[buf][j64] = pxw + rd + bias_r;
            if (t == Tc - 1) {
                #pragma unroll
                for (int r = 0; r < 16; ++r)
                    Ffin[((size_t)bg * Hc + c0 + fci) * 16 + r] = F_lds[j64][r];
            } else {
                const size_t row = (size_t)bg * Tc + (t + 1);
                plam = lamg[row];
                pv   = vg[row * Hc + c0 + fci];
                pxw  = out0[row * Hc + c0 + fci];
                const float* qp  = qg + row * 16;
                const float* kpp = kg + row * 16;
                #pragma unroll
                for (int r4 = 0; r4 < 4; ++r4) {
                    pq[r4]  = *(const float4*)(qp + r4 * 4);
                    pk4[r4] = *(const float4*)(kpp + r4 * 4);
                }
            }
        }

        // ---- poll own 8-value window, stage into hs ----
        if (t > 0) {
            const float lo = off_r - 1.5f, hi = off_r + 1.5f;
            const float* p0 = h_rd + sb_ * 1024 + f;
            const float* p1 = p0 + 4;
            float4 r0, r1;
            int tries = 0;
            for (;;) {
                if (fastf) {
                    asm volatile(
                        "global_load_dwordx4 %0, %2, off sc0\n\t"
                        "global_load_dwordx4 %1, %3, off sc0\n\t"
                        "s_waitcnt vmcnt(0)"
                        : "=&v"(r0), "=&v"(r1)
                        : "v"(p0), "v"(p1) : "memory");
                } else {
                    asm volatile(
                        "global_load_dwordx4 %0, %2, off sc0 sc1\n\t"
                        "global_load_dwordx4 %1, %3, off sc0 sc1\n\t"
                        "s_waitcnt vmcnt(0)"
                        : "=&v"(r0), "=&v"(r1)
                        : "v"(p0), "v"(p1) : "memory");
                }
                bool ok = r0.x > lo && r0.x < hi && r0.y > lo && r0.y < hi
                       && r0.z > lo && r0.z < hi && r0.w > lo && r0.w < hi
                       && r1.x > lo && r1.x < hi && r1.y > lo && r1.y < hi
                       && r1.z > lo && r1.z < hi && r1.w > lo && r1.w < hi;
                if (ok) break;
                if (fastf && ++tries > 64) fastf = 0;  // sticky escalation
            }
            r0.x -= off_r; r0.y -= off_r; r0.z -= off_r; r0.w -= off_r;
            r1.x -= off_r; r1.y -= off_r; r1.z -= off_r; r1.w -= off_r;
            *(float4*)(stage_base)     = r0;
            *(float4*)(stage_base + 4) = r1;
        } else {
            float4 z = {0.f, 0.f, 0.f, 0.f};
            *(float4*)(stage_base)     = z;
            *(float4*)(stage_base + 4) = z;
        }
        __syncthreads();                       // B: hs ready

        // ---- matvec: 16 b128 LDS reads, 256 FMAs per thread ----
        float acc[8];
        #pragma unroll
        for (int z = 0; z < 8; ++z) acc[z] = 0.f;
        #pragma unroll
        for (int bb = 0; bb < 2; ++bb) {
            const float* hb = &hs[bb * 1152 + kp * 36];
            #pragma unroll
            for (int i = 0; i < 8; ++i) {
                float4 h4 = *(const float4*)(hb + i * 4);
                #pragma unroll
                for (int j = 0; j < 4; ++j)
                    acc[j * 2 + bb] += h4.x * wr[(i * 4 + 0) * 4 + j]
                                     + h4.y * wr[(i * 4 + 1) * 4 + j]
                                     + h4.z * wr[(i * 4 + 2) * 4 + j]
                                     + h4.w * wr[(i * 4 + 3) * 4 + j];
            }
        }

        // ---- butterfly over the wave's 8 k-parts (lane bits 3,4,5) ----
        #pragma unroll
        for (int z = 0; z < 8; ++z) {
            float s = acc[z];
            s += __shfl_xor(s, 8);
            s += __shfl_xor(s, 16);
            s += __shfl_xor(s, 32);
            acc[z] = s;
        }
        if (j64 < 8) {                          // one lane per cu
            float4 ra, rb;
            ra.x = acc[0]; ra.y = acc[1]; ra.z = acc[2]; ra.w = acc[3];
            rb.x = acc[4]; rb.y = acc[5]; rb.z = acc[6]; rb.w = acc[7];
            *(float4*)&red2[buf][wv * 64 + j64 * 8]     = ra;
            *(float4*)&red2[buf][wv * 64 + j64 * 8 + 4] = rb;
        }
        __syncthreads();                       // C: red2 + pre_lds ready

        // ---- finisher: combine 4 wave-partials, tanh, DUAL publish ----
        if (isFin) {
            const int cu_f = fci >> 2, jf = fci & 3;
            const int z = jf * 2 + fb;
            float tot = pre_lds[buf][j64];
            #pragma unroll
            for (int ww = 0; ww < 4; ++ww)
                tot += red2[buf][ww * 64 + cu_f * 8 + z];
            float hv = tanhf(tot);
            float sv = hv + off_w;             // self-signaling value
            float* hp = h_wr + fb * 1024 + c0 + fci;
            // (1) sc0: leaves a valid line in the shared XCD L2 (fast polls)
            asm volatile("global_store_dword %0, %1, off sc0"
                         :: "v"(hp), "v"(sv) : "memory");
            // (2) sc0 sc1: device coherence point (slow/escalated polls)
            asm volatile("global_store_dword %0, %1, off sc0 sc1"
                         :: "v"(hp), "v"(sv) : "memory");
            size_t oidx = ((size_t)bg * Tc + t) * Hc + c0 + fci;
            out0[oidx] = hv;
            if (t == Tc - 1) hfin[(size_t)bg * Hc + c0 + fci] = hv;
        }
    }
}

// ---------------------------------------------------------------------------
extern "C" void kernel_launch(void* const* d_in, const int* in_sizes, int n_in,
                              void* d_out, int out_size, void* d_ws, size_t ws_size,
                              hipStream_t stream)
{
    const float* x    = (const float*)d_in[0];
    const float* Wx   = (const float*)d_in[1];
    const float* Wh   = (const float*)d_in[2];
    const float* Wq   = (const float*)d_in[3];
    const float* Wk   = (const float*)d_in[4];
    const float* Wv   = (const float*)d_in[5];
    const float* Wd   = (const float*)d_in[6];
    const float* bias = (const float*)d_in[7];
    const float* bd   = (const float*)d_in[8];

    float* out0 = (float*)d_out;                    // (B,T,H): xw, then h
    float* hfin = out0 + (size_t)Bc * Tc * Hc;      // (B,H)
    float* Ffin = hfin + (size_t)Bc * Hc;           // (B,H,R)

    float* wsf  = (float*)d_ws;
    float* v    = wsf;                               // B*T*H
    float* q    = v + (size_t)Bc * Tc * Hc;          // B*T*R
    float* k    = q + (size_t)Bc * Tc * Rc;          // B*T*R
    float* lam  = k + (size_t)Bc * Tc * Rc;          // B*T
    float* hbuf = lam + (size_t)Bc * Tc;             // 2 * B*H ping-pong
    int*   xcc  = (int*)(hbuf + 2 * (size_t)Bc * Hc);// 256 entries

    // 0x7F7F7F7F == 3.39e38f: invalid under both offsets -> poll-safe init.
    hipMemsetAsync(hbuf, 0x7F, 2 * (size_t)Bc * Hc * sizeof(float), stream);
    hipMemsetAsync(xcc, 0xFF, 256 * sizeof(int), stream);

    dim3 gp(256, 8, 3);
    proj_fused<<<gp, 256, 0, stream>>>(x, Wx, Wv, Wq, Wk, Wd, bd,
                                       out0, v, q, k, lam);
    rec_fused<<<256, 256, 0, stream>>>(Wh, q, k, v, lam, bias,
                                       out0, hfin, Ffin, hbuf, xcc);
}

// Round 17
// 7582.481 us; speedup vs baseline: 1.9491x; 1.0283x over previous
//
#include <hip/hip_runtime.h>
#include <math.h>

#define Bc 16
#define Tc 2048
#define Dc 512
#define Hc 1024
#define Rc 16

// ---------------------------------------------------------------------------
// Merged projection kernel. One dispatch, grid (256, 8, 3):
//   z=0: xw = X@Wx   (BM=128, BN=128, 8x8 micro-tile)
//   z=1: v  = X@Wv   (same)
//   z=2: q/k/lambda  (block = 16 rows of x staged in LDS; 528 dots)
// ---------------------------------------------------------------------------
__global__ __launch_bounds__(256) void proj_fused(const float* __restrict__ X,
    const float* __restrict__ Wx, const float* __restrict__ Wv,
    const float* __restrict__ Wq, const float* __restrict__ Wk,
    const float* __restrict__ Wd, const float* __restrict__ bd,
    float* __restrict__ out0, float* __restrict__ vout,
    float* __restrict__ q, float* __restrict__ k, float* __restrict__ lam)
{
    __shared__ float smem[8192];   // 32 KB, shared by both paths
    const int tid = threadIdx.x;

    if (blockIdx.z < 2) {
        // ---------------- GEMM path ----------------
        float (*As)[128] = (float (*)[128])smem;          // [16][128]
        float (*Bs)[128] = (float (*)[128])(smem + 2048); // [16][128]
        const float* W = blockIdx.z ? Wv : Wx;
        float* out     = blockIdx.z ? vout : out0;
        const int m0 = blockIdx.x * 128;
        const int n0 = blockIdx.y * 128;
        const int tx = tid & 15, ty = tid >> 4;
        const int ar = tid >> 1, ak = (tid & 1) * 8;
        const int br = tid >> 4, bn = (tid & 15) * 8;
        float acc[8][8] = {};
        for (int k0 = 0; k0 < 512; k0 += 16) {
            if (k0) __syncthreads();
            float4 a0 = *(const float4*)&X[(size_t)(m0 + ar) * 512 + k0 + ak];
            float4 a1 = *(const float4*)&X[(size_t)(m0 + ar) * 512 + k0 + ak + 4];
            float4 b0 = *(const float4*)&W[(size_t)(k0 + br) * 1024 + n0 + bn];
            float4 b1 = *(const float4*)&W[(size_t)(k0 + br) * 1024 + n0 + bn + 4];
            As[ak + 0][ar] = a0.x; As[ak + 1][ar] = a0.y;
            As[ak + 2][ar] = a0.z; As[ak + 3][ar] = a0.w;
            As[ak + 4][ar] = a1.x; As[ak + 5][ar] = a1.y;
            As[ak + 6][ar] = a1.z; As[ak + 7][ar] = a1.w;
            *(float4*)&Bs[br][bn]     = b0;
            *(float4*)&Bs[br][bn + 4] = b1;
            __syncthreads();
            #pragma unroll
            for (int kk = 0; kk < 16; ++kk) {
                float4 xa = *(const float4*)&As[kk][ty * 8];
                float4 xb = *(const float4*)&As[kk][ty * 8 + 4];
                float4 ya = *(const float4*)&Bs[kk][tx * 8];
                float4 yb = *(const float4*)&Bs[kk][tx * 8 + 4];
                float a[8] = {xa.x, xa.y, xa.z, xa.w, xb.x, xb.y, xb.z, xb.w};
                float b[8] = {ya.x, ya.y, ya.z, ya.w, yb.x, yb.y, yb.z, yb.w};
                #pragma unroll
                for (int i = 0; i < 8; ++i)
                    #pragma unroll
                    for (int j = 0; j < 8; ++j)
                        acc[i][j] += a[i] * b[j];
            }
        }
        #pragma unroll
        for (int i = 0; i < 8; ++i) {
            float4 r0, r1;
            r0.x = acc[i][0]; r0.y = acc[i][1]; r0.z = acc[i][2]; r0.w = acc[i][3];
            r1.x = acc[i][4]; r1.y = acc[i][5]; r1.z = acc[i][6]; r1.w = acc[i][7];
            float* op = &out[(size_t)(m0 + ty * 8 + i) * 1024 + n0 + tx * 8];
            *(float4*)op       = r0;
            *(float4*)(op + 4) = r1;
        }
    } else {
        // ---------------- q/k/lambda path ----------------
        float* xs = smem;                                  // 16 rows x 512
        const int rb = blockIdx.x * 8 + blockIdx.y;        // 0..2047
        const size_t row0 = (size_t)rb * 16;
        #pragma unroll
        for (int c = 0; c < 8; ++c) {
            int f = (c * 256 + tid) * 4;
            *(float4*)&xs[f] = *(const float4*)&X[row0 * 512 + f];
        }
        __syncthreads();
        for (int t = tid; t < 528; t += 256) {
            int r = t / 33, c = t - r * 33;
            const float* xr = &xs[r * 512];
            const float* Wp; int ldw;
            if (c < 16)      { Wp = Wq + c;        ldw = 16; }
            else if (c < 32) { Wp = Wk + (c - 16); ldw = 16; }
            else             { Wp = Wd;            ldw = 1;  }
            float s = 0.f;
            for (int kk = 0; kk < 512; ++kk) s += xr[kk] * Wp[(size_t)kk * ldw];
            if (c < 16)      q[(row0 + r) * 16 + c] = s;
            else if (c < 32) k[(row0 + r) * 16 + (c - 16)] = s;
            else             lam[row0 + r] = 1.f / (1.f + expf(-(s + bd[0])));
        }
    }
}

// ---------------------------------------------------------------------------
// Fused recurrence — byte-identical to the R13-proven kernel (best: 6.6 ms):
// XCD-local exchange groups, per-thread fast/slow scope select with sticky
// escalation, wave3 fused fast-weight scan, 4-wave matvec + butterfly,
// wave0 finisher, single sc0 sc1 publish (R16's dual-store REGRESSED:
// the sc1 write-through invalidates the sc0-deposited L2 line).
// DO NOT enlarge per-thread state (R10/R12/R15: weight spill at VGPR<184).
// ---------------------------------------------------------------------------
__global__ __launch_bounds__(256, 1) void rec_fused(
    const float* __restrict__ Wh, const float* __restrict__ qg,
    const float* __restrict__ kg, const float* __restrict__ vg,
    const float* __restrict__ lamg, const float* __restrict__ bias,
    float* __restrict__ out0, float* __restrict__ hfin,
    float* __restrict__ Ffin, float* __restrict__ hbuf,
    int* __restrict__ xcc_tab)
{
    __shared__ float hs[2 * 1152];     // phys(b,k) = b*1152 + (k>>5)*36 + (k&31)
    __shared__ float red2[2][256];     // [buf][wave*64 + cu*8 + z]
    __shared__ float pre_lds[2][64];   // [buf][bb*32 + ci]
    __shared__ float F_lds[64][17];    // fast-weight state, pad 17

    const int tid = threadIdx.x;
    const int bid = blockIdx.x;
    const int g = bid & 7, sl = bid >> 3;
    const int c0 = sl * 32;
    const int kp = tid >> 3;          // k-part: 32 k's (kp*32 .. +31)
    const int cu = tid & 7;           // col unit: 4 cols (c0 + cu*4 + j)
    const int wv = tid >> 6;

    // ---- publish my XCD id (value xcc+1; table memset to 0xFF each launch)
    const int my_xcc = __builtin_amdgcn_s_getreg(63508) & 0xF; // hwreg XCC_ID
    if (tid == 0) {
        int val = my_xcc + 1;
        int* tp = xcc_tab + bid;
        asm volatile("global_store_dword %0, %1, off sc0 sc1"
                     :: "v"(tp), "v"(val) : "memory");
    }

    // ---- weights: 128 regs/thread, all indices compile-time
    float wr[128];
    #pragma unroll
    for (int i = 0; i < 32; ++i) {
        float4 w4 = *(const float4*)&Wh[(size_t)(kp * 32 + i) * 1024 + c0 + cu * 4];
        wr[i * 4 + 0] = w4.x; wr[i * 4 + 1] = w4.y;
        wr[i * 4 + 2] = w4.z; wr[i * 4 + 3] = w4.w;
    }

    // ---- stage/poll geometry: thread owns 8 h values of one batch
    const int sb_ = tid >> 7;                // batch-in-group 0/1
    const int f   = (tid & 127) * 8;         // col offset 0..1016
    float* stage_base = &hs[sb_ * 1152 + (f >> 5) * 36 + (f & 31)];

    // ---- scope detect: producer of my window
    int fastf;
    {
        const int prod_bid = (f >> 5) * 8 + g;
        const int* tp = xcc_tab + prod_bid;
        int tv;
        for (;;) {
            asm volatile("global_load_dword %0, %1, off sc0 sc1\n\t"
                         "s_waitcnt vmcnt(0)"
                         : "=&v"(tv) : "v"(tp) : "memory");
            if (tv != -1) break;
        }
        fastf = ((tv - 1) == my_xcc) ? 1 : 0;
    }

    // ---- roles
    const int j64 = tid & 63;
    const int fb = j64 >> 5, fci = j64 & 31;   // (batch-in-group, col-in-slice)
    const int bg = g * 2 + fb;                 // global batch
    const bool isScan = (tid >= 192);
    const bool isFin  = (tid < 64);

    float bias_r = 0.f, plam = 0.f, pv = 0.f, pxw = 0.f;
    float4 pq[4], pk4[4];
    if (isScan) {
        bias_r = bias[c0 + fci];
        #pragma unroll
        for (int r = 0; r < 16; ++r) F_lds[j64][r] = 0.f;
        const size_t row = (size_t)bg * Tc;             // t = 0 inputs
        plam = lamg[row];
        pv   = vg[row * Hc + c0 + fci];
        pxw  = out0[row * Hc + c0 + fci];
        const float* qp  = qg + row * 16;
        const float* kpp = kg + row * 16;
        #pragma unroll
        for (int r4 = 0; r4 < 4; ++r4) {
            pq[r4]  = *(const float4*)(qp + r4 * 4);
            pk4[r4] = *(const float4*)(kpp + r4 * 4);
        }
    }

    for (int t = 0; t < Tc; ++t) {
        const int buf = t & 1;
        float* h_rd = hbuf + (t & 1) * (16 * 1024) + g * 2048;
        float* h_wr = hbuf + ((t + 1) & 1) * (16 * 1024) + g * 2048;
        const float off_r = ((t >> 1) & 1) ? 4.0f : 0.0f;
        const float off_w = (((t + 1) >> 1) & 1) ? 4.0f : 0.0f;

        // ---- wave3: fast-weight scan (hidden under the poll) ----
        if (isScan) {
            float rd = 0.f;
            #pragma unroll
            for (int r4 = 0; r4 < 4; ++r4) {
                float f0 = F_lds[j64][r4 * 4 + 0];
                float f1 = F_lds[j64][r4 * 4 + 1];
                float f2 = F_lds[j64][r4 * 4 + 2];
                float f3 = F_lds[j64][r4 * 4 + 3];
                f0 = plam * f0 + pv * pk4[r4].x; rd += f0 * pq[r4].x;
                f1 = plam * f1 + pv * pk4[r4].y; rd += f1 * pq[r4].y;
                f2 = plam * f2 + pv * pk4[r4].z; rd += f2 * pq[r4].z;
                f3 = plam * f3 + pv * pk4[r4].w; rd += f3 * pq[r4].w;
                F_lds[j64][r4 * 4 + 0] = f0;
                F_lds[j64][r4 * 4 + 1] = f1;
                F_lds[j64][r4 * 4 + 2] = f2;
                F_lds[j64][r4 * 4 + 3] = f3;
            }
            pre_lds[buf][j64] = pxw + rd + bias_r;
            if (t == Tc - 1) {
                #pragma unroll
                for (int r = 0; r < 16; ++r)
                    Ffin[((size_t)bg * Hc + c0 + fci) * 16 + r] = F_lds[j64][r];
            } else {
                const size_t row = (size_t)bg * Tc + (t + 1);
                plam = lamg[row];
                pv   = vg[row * Hc + c0 + fci];
                pxw  = out0[row * Hc + c0 + fci];
                const float* qp  = qg + row * 16;
                const float* kpp = kg + row * 16;
                #pragma unroll
                for (int r4 = 0; r4 < 4; ++r4) {
                    pq[r4]  = *(const float4*)(qp + r4 * 4);
                    pk4[r4] = *(const float4*)(kpp + r4 * 4);
                }
            }
        }

        // ---- poll own 8-value window, stage into hs ----
        if (t > 0) {
            const float lo = off_r - 1.5f, hi = off_r + 1.5f;
            const float* p0 = h_rd + sb_ * 1024 + f;
            const float* p1 = p0 + 4;
            float4 r0, r1;
            int tries = 0;
            for (;;) {
                if (fastf) {
                    asm volatile(
                        "global_load_dwordx4 %0, %2, off sc0\n\t"
                        "global_load_dwordx4 %1, %3, off sc0\n\t"
                        "s_waitcnt vmcnt(0)"
                        : "=&v"(r0), "=&v"(r1)
                        : "v"(p0), "v"(p1) : "memory");
                } else {
                    asm volatile(
                        "global_load_dwordx4 %0, %2, off sc0 sc1\n\t"
                        "global_load_dwordx4 %1, %3, off sc0 sc1\n\t"
                        "s_waitcnt vmcnt(0)"
                        : "=&v"(r0), "=&v"(r1)
                        : "v"(p0), "v"(p1) : "memory");
                }
                bool ok = r0.x > lo && r0.x < hi && r0.y > lo && r0.y < hi
                       && r0.z > lo && r0.z < hi && r0.w > lo && r0.w < hi
                       && r1.x > lo && r1.x < hi && r1.y > lo && r1.y < hi
                       && r1.z > lo && r1.z < hi && r1.w > lo && r1.w < hi;
                if (ok) break;
                if (fastf && ++tries > 64) fastf = 0;  // sticky escalation
            }
            r0.x -= off_r; r0.y -= off_r; r0.z -= off_r; r0.w -= off_r;
            r1.x -= off_r; r1.y -= off_r; r1.z -= off_r; r1.w -= off_r;
            *(float4*)(stage_base)     = r0;
            *(float4*)(stage_base + 4) = r1;
        } else {
            float4 z = {0.f, 0.f, 0.f, 0.f};
            *(float4*)(stage_base)     = z;
            *(float4*)(stage_base + 4) = z;
        }
        __syncthreads();                       // B: hs ready

        // ---- matvec: 16 b128 LDS reads, 256 FMAs per thread ----
        float acc[8];
        #pragma unroll
        for (int z = 0; z < 8; ++z) acc[z] = 0.f;
        #pragma unroll
        for (int bb = 0; bb < 2; ++bb) {
            const float* hb = &hs[bb * 1152 + kp * 36];
            #pragma unroll
            for (int i = 0; i < 8; ++i) {
                float4 h4 = *(const float4*)(hb + i * 4);
                #pragma unroll
                for (int j = 0; j < 4; ++j)
                    acc[j * 2 + bb] += h4.x * wr[(i * 4 + 0) * 4 + j]
                                     + h4.y * wr[(i * 4 + 1) * 4 + j]
                                     + h4.z * wr[(i * 4 + 2) * 4 + j]
                                     + h4.w * wr[(i * 4 + 3) * 4 + j];
            }
        }

        // ---- butterfly over the wave's 8 k-parts (lane bits 3,4,5) ----
        #pragma unroll
        for (int z = 0; z < 8; ++z) {
            float s = acc[z];
            s += __shfl_xor(s, 8);
            s += __shfl_xor(s, 16);
            s += __shfl_xor(s, 32);
            acc[z] = s;
        }
        if (j64 < 8) {                          // one lane per cu
            float4 ra, rb;
            ra.x = acc[0]; ra.y = acc[1]; ra.z = acc[2]; ra.w = acc[3];
            rb.x = acc[4]; rb.y = acc[5]; rb.z = acc[6]; rb.w = acc[7];
            *(float4*)&red2[buf][wv * 64 + j64 * 8]     = ra;
            *(float4*)&red2[buf][wv * 64 + j64 * 8 + 4] = rb;
        }
        __syncthreads();                       // C: red2 + pre_lds ready

        // ---- finisher: combine 4 wave-partials, tanh, store ----
        if (isFin) {
            const int cu_f = fci >> 2, jf = fci & 3;
            const int z = jf * 2 + fb;
            float tot = pre_lds[buf][j64];
            #pragma unroll
            for (int ww = 0; ww < 4; ++ww)
                tot += red2[buf][ww * 64 + cu_f * 8 + z];
            float hv = tanhf(tot);
            float sv = hv + off_w;             // self-signaling store first
            float* hp = h_wr + fb * 1024 + c0 + fci;
            asm volatile(
                "global_store_dword %0, %1, off sc0 sc1"
                :: "v"(hp), "v"(sv) : "memory");
            size_t oidx = ((size_t)bg * Tc + t) * Hc + c0 + fci;
            out0[oidx] = hv;
            if (t == Tc - 1) hfin[(size_t)bg * Hc + c0 + fci] = hv;
        }
    }
}

// ---------------------------------------------------------------------------
extern "C" void kernel_launch(void* const* d_in, const int* in_sizes, int n_in,
                              void* d_out, int out_size, void* d_ws, size_t ws_size,
                              hipStream_t stream)
{
    const float* x    = (const float*)d_in[0];
    const float* Wx   = (const float*)d_in[1];
    const float* Wh   = (const float*)d_in[2];
    const float* Wq   = (const float*)d_in[3];
    const float* Wk   = (const float*)d_in[4];
    const float* Wv   = (const float*)d_in[5];
    const float* Wd   = (const float*)d_in[6];
    const float* bias = (const float*)d_in[7];
    const float* bd   = (const float*)d_in[8];

    float* out0 = (float*)d_out;                    // (B,T,H): xw, then h
    float* hfin = out0 + (size_t)Bc * Tc * Hc;      // (B,H)
    float* Ffin = hfin + (size_t)Bc * Hc;           // (B,H,R)

    float* wsf  = (float*)d_ws;
    float* v    = wsf;                               // B*T*H
    float* q    = v + (size_t)Bc * Tc * Hc;          // B*T*R
    float* k    = q + (size_t)Bc * Tc * Rc;          // B*T*R
    float* lam  = k + (size_t)Bc * Tc * Rc;          // B*T
    float* hbuf = lam + (size_t)Bc * Tc;             // 2 * B*H ping-pong
    int*   xcc  = (int*)(hbuf + 2 * (size_t)Bc * Hc);// 256 entries

    // 0x7F7F7F7F == 3.39e38f: invalid under both offsets -> poll-safe init.
    hipMemsetAsync(hbuf, 0x7F, 2 * (size_t)Bc * Hc * sizeof(float), stream);
    hipMemsetAsync(xcc, 0xFF, 256 * sizeof(int), stream);

    dim3 gp(256, 8, 3);
    proj_fused<<<gp, 256, 0, stream>>>(x, Wx, Wv, Wq, Wk, Wd, bd,
                                       out0, v, q, k, lam);
    rec_fused<<<256, 256, 0, stream>>>(Wh, q, k, v, lam, bias,
                                       out0, hfin, Ffin, hbuf, xcc);
}